// Round 14
// baseline (5608.057 us; speedup 1.0000x reference)
//
#include <hip/hip_runtime.h>

#define B 64
#define T 256
#define H 512
#define G4 2048
#define D0 128
#define NL 6
#define NBLK_P 192            // 6 layers x 32 col-groups
#define SKEW 2                // layer skew (inter-layer slack = 1 step)
#define GTOT (T + SKEW * (NL - 1))   // 266 global steps
#define FSTRIDE 16            // u32 stride between per-block flags (64B)
#define RD 8                  // ring depth (slots/layer); WAR slack = 5
#define GSTR 36               // g_par row-dim stride, f32 (32 + 4)

typedef float f32x4 __attribute__((ext_vector_type(4)));
typedef float f32x16 __attribute__((ext_vector_type(16)));
typedef _Float16 h16x8 __attribute__((ext_vector_type(8)));

// Coherent 16B load (proven r9-r13): reads at the coherence point, immune to
// stale per-XCD L2 copies of reused ring slots.
#define CLOAD(dst, p) \
  asm volatile("global_load_dwordx4 %0, %1, off sc0 sc1" : "=&v"(dst) : "v"(p))
#define VMWAIT do { asm volatile("s_waitcnt vmcnt(0)" ::: "memory"); \
                    __builtin_amdgcn_sched_barrier(0); } while (0)

// ===========================================================================
// lstm_pipe v6 — per-wave dataflow. r12's math bit-identical; structure:
//  * B-frags loaded PER-WAVE straight into registers from the (linear, r12)
//    ring — the whole LDS h_s staging phase (write+sync+read) is deleted.
//    LDS holds only g_par. Syncs/step: 5 -> 2.
//  * Per-wave wake: each wave polls flags itself (__all), then loads+MFMAs
//    without waiting for sibling waves. Step-entry is still block-coherent
//    because the OWN-block flag (stored after the step-g-1 drain sync) gates
//    every wave's poll -> no wave enters step g before the block finished
//    g-1 -> g_par WAR safe.
//  * LOCAL flags, skew-2, 8-deep ring: t = g - 2l. Waits:
//      own layer  >= g    (tight — the true recurrence edge)
//      layer l-1  >= g-1  (slack 1: h_{l-1}(t) published at g-2)
//      layer l+1  >= g-5  (WAR: slot t%8 last read by l+1 at step g-6)
//    Writer-side ahead-run is bounded symmetrically: l-1 overwriting our
//    rgA slot (its step g+6) needs OUR flag >= g+1 -> blocked until we
//    finish g. No global 192-block convoy.
//  * t==0: h(-1)=0 handled by SKIPPING the inB MFMAs (adding exact zeros).
// ===========================================================================
__global__ void __launch_bounds__(1024, 4) lstm_pipe(
    const float* __restrict__ x,
    const float* __restrict__ Wih0, const float* __restrict__ WihR,
    const float* __restrict__ Whh,
    const float* __restrict__ bih, const float* __restrict__ bhh,
    unsigned short* __restrict__ ring, float* __restrict__ h5,
    unsigned* __restrict__ flags)
{
  __shared__ float g_par[4 * 4 * 32 * GSTR];   // 73728 B — the only LDS

  const int tid  = threadIdx.x;
  const int lane = tid & 63;
  const int wl   = __builtin_amdgcn_readfirstlane(tid >> 6);
  const int ks   = wl & 3;                  // k-slice (256 k)
  const int rt   = (wl >> 2) >> 1;          // C row-tile (32 rows)
  const int bt   = (wl >> 2) & 1;           // C batch-tile (32 cols)
  const int blk  = (int)blockIdx.x;
  const int l    = blk >> 5;                // layer
  const int jb   = blk & 31;
  const int j0   = jb * 16;                 // owned cols j0..j0+15
  const int Kin  = (l == 0) ? D0 : H;
  const int KTOT = Kin + 512;               // 640 or 1024

  const float* WihA = (l == 0) ? Wih0 : (WihR + (size_t)(l - 1) * G4 * H);
  const float* WhhA = Whh + (size_t)l * G4 * H;

  // ---- one-time: W slice -> A-fragments in registers (r12 verbatim) ----
  h16x8 a[16];
  {
    const int ri   = rt * 32 + (lane & 31);
    const int grow = (ri >> 4) * H + j0 + (ri & 15);
    const float* wihRow = WihA + (size_t)grow * Kin;
    const float* whhRow = WhhA + (size_t)grow * H;
    const int klane = (lane >> 5) * 8;
#pragma unroll
    for (int m = 0; m < 16; ++m) {
      int kb = ks * 256 + m * 16;
      h16x8 f = {};
      if (kb < KTOT) {
        const float* src = (kb < Kin) ? (wihRow + kb + klane)
                                      : (whhRow + (kb - Kin) + klane);
        f32x4 v0 = *(const f32x4*)src;
        f32x4 v1 = *(const f32x4*)(src + 4);
        f[0] = (_Float16)v0.x; f[1] = (_Float16)v0.y;
        f[2] = (_Float16)v0.z; f[3] = (_Float16)v0.w;
        f[4] = (_Float16)v1.x; f[5] = (_Float16)v1.y;
        f[6] = (_Float16)v1.z; f[7] = (_Float16)v1.w;
      }
      a[m] = f;
    }
  }

  // pointwise ownership + bias (r12 verbatim)
  const int pb = tid >> 4, pcj = tid & 15;
  float bias4[4];
#pragma unroll
  for (int gi = 0; gi < 4; ++gi) {
    int grow = gi * H + j0 + pcj;
    bias4[gi] = bih[(size_t)l * G4 + grow] + bhh[(size_t)l * G4 + grow];
  }

  // B-frag addressing: batch row + k-offset within frag
  const int brow = bt * 32 + (lane & 31);
  const int koff = (lane >> 5) * 8;

  // poll mapping: every lane checks own-layer flag (lane&31); lanes 0-31
  // additionally check l-1 (thr g-1), lanes 32-63 check l+1 (thr g-5)
  const int li = lane & 31;
  unsigned* const f_own = &flags[(l * 32 + li) * FSTRIDE];
  unsigned* const f_nb =
      (lane < 32) ? ((l > 0)      ? &flags[((l - 1) * 32 + li) * FSTRIDE]
                                  : (unsigned*)0)
                  : ((l < NL - 1) ? &flags[((l + 1) * 32 + li) * FSTRIDE]
                                  : (unsigned*)0);
  const int nb_lag = (lane < 32) ? 1 : 5;

  float creg = 0.f;

  for (int g = 0; g < GTOT; ++g) {
    const int t = g - SKEW * l;
    const bool active = (t >= 0) && (t < T);

    if (g > 0) {   // per-wave local wait
      for (;;) {
        int ok = ((int)__hip_atomic_load(f_own, __ATOMIC_RELAXED,
                                         __HIP_MEMORY_SCOPE_AGENT) >= g);
        if (f_nb)
          ok &= ((int)__hip_atomic_load(f_nb, __ATOMIC_RELAXED,
                                        __HIP_MEMORY_SCOPE_AGENT) >= g - nb_lag);
        if (__all(ok)) break;
        __builtin_amdgcn_s_sleep(1);
      }
      asm volatile("" ::: "memory");
      __builtin_amdgcn_sched_barrier(0);
    }

    if (active) {
      const unsigned short* rgA =
          ring + ((size_t)(l - 1) * RD + (t & (RD - 1))) * (B * H);   // l>0
      const unsigned short* rgB =
          ring + ((size_t)l * RD + ((t - 1) & (RD - 1))) * (B * H);

      // ---- pass 1: issue B-frag loads into rr[16] ----
      f32x4 rr[16];
#pragma unroll
      for (int m = 0; m < 16; ++m) {
        const int kbase = ks * 256 + m * 16;
        if (kbase >= KTOT) continue;
        const int kb = kbase + koff;
        if (kbase < Kin) {
          if (l == 0) {   // x: plain f32 loads + cvt (compiler auto-waits)
            const float* xr = x + ((size_t)brow * T + t) * D0 + kb;
            f32x4 v0 = *(const f32x4*)xr;
            f32x4 v1 = *(const f32x4*)(xr + 4);
            h16x8 f;
            f[0] = (_Float16)v0.x; f[1] = (_Float16)v0.y;
            f[2] = (_Float16)v0.z; f[3] = (_Float16)v0.w;
            f[4] = (_Float16)v1.x; f[5] = (_Float16)v1.y;
            f[6] = (_Float16)v1.z; f[7] = (_Float16)v1.w;
            rr[m] = __builtin_bit_cast(f32x4, f);
          } else {
            CLOAD(rr[m], rgA + (size_t)brow * H + kb);
          }
        } else if (t > 0) {
          CLOAD(rr[m], rgB + (size_t)brow * H + (kb - Kin));
        }
      }
      VMWAIT;   // all CLOADs resident

      // ---- pass 2: 16 MFMAs (t==0 skips inB terms: exact +0) ----
      f32x16 accv = {};
#pragma unroll
      for (int m = 0; m < 16; ++m) {
        const int kbase = ks * 256 + m * 16;
        if (kbase >= KTOT) continue;
        if (kbase >= Kin && t == 0) continue;
        h16x8 b8 = __builtin_bit_cast(h16x8, rr[m]);
        accv = __builtin_amdgcn_mfma_f32_32x32x16_f16(a[m], b8, accv, 0, 0, 0);
      }

      // ---- k-slice partials -> g_par (r12 verbatim) ----
      {
        float* gp = g_par +
            (size_t)((ks * 4 + (rt * 2 + bt)) * 32 + (lane & 31)) * GSTR +
            4 * (lane >> 5);
#pragma unroll
        for (int q = 0; q < 4; ++q) {
          f32x4 tv;
          tv.x = accv[4 * q];     tv.y = accv[4 * q + 1];
          tv.z = accv[4 * q + 2]; tv.w = accv[4 * q + 3];
          *(f32x4*)&gp[8 * q] = tv;
        }
      }
      __syncthreads();   // sync1: all g_par written

      // ---- reduce + bias + pointwise + publish (r12 verbatim) ----
      {
        float gt[4];
#pragma unroll
        for (int gi = 0; gi < 4; ++gi) {
          int rowL = gi * 16 + pcj;
          int tile = (rowL >> 5) * 2 + (pb >> 5);
          int rL   = rowL & 31;
          float s = bias4[gi];
#pragma unroll
          for (int ksi = 0; ksi < 4; ++ksi)
            s += g_par[(size_t)((ksi * 4 + tile) * 32 + (pb & 31)) * GSTR + rL];
          gt[gi] = s;
        }
        float iv = 1.f / (1.f + expf(-gt[0]));
        float fv = 1.f / (1.f + expf(-gt[1]));
        float gv = tanhf(gt[2]);
        float ov = 1.f / (1.f + expf(-gt[3]));
        creg = fv * creg + iv * gv;
        float hv = ov * tanhf(creg);
        _Float16 hf = (_Float16)hv;
        __hip_atomic_store(
            &ring[((size_t)l * RD + (t & (RD - 1))) * (B * H) + pb * H + j0 + pcj],
            __builtin_bit_cast(unsigned short, hf),
            __ATOMIC_RELAXED, __HIP_MEMORY_SCOPE_AGENT);
        if (l == NL - 1 && t == T - 1)
          h5[pb * H + j0 + pcj] = hv;    // f32 copy for FC precision
      }
      __syncthreads();   // sync2: drain publish stores before flagging
    }

    if (tid == 0)
      __hip_atomic_store(&flags[blk * FSTRIDE], (unsigned)(g + 1),
                         __ATOMIC_RELAXED, __HIP_MEMORY_SCOPE_AGENT);
  }
}

// ===========================================================================
// Final FC on h_5(T-1) (f32 side buffer)
// ===========================================================================
__global__ void __launch_bounds__(640) fc_kernel(
    const float* __restrict__ h5, const float* __restrict__ w,
    const float* __restrict__ bias, float* __restrict__ out)
{
  int tid = threadIdx.x;
  if (tid >= 640) return;
  int b = tid / 10, o = tid - b * 10;
  const float* yr = h5 + (size_t)b * H;
  const float* wr = w + (size_t)o * H;
  float acc = bias[o];
  for (int k = 0; k < H; ++k) acc = fmaf(yr[k], wr[k], acc);
  out[b * 10 + o] = acc;
}

extern "C" void kernel_launch(void* const* d_in, const int* in_sizes, int n_in,
                              void* d_out, int out_size, void* d_ws,
                              size_t ws_size, hipStream_t stream)
{
  const float* x    = (const float*)d_in[0];
  const float* Wih0 = (const float*)d_in[1];
  const float* WihR = (const float*)d_in[2];
  const float* Whh  = (const float*)d_in[3];
  const float* bih  = (const float*)d_in[4];
  const float* bhh  = (const float*)d_in[5];
  const float* fcw  = (const float*)d_in[6];
  const float* fcb  = (const float*)d_in[7];
  float* out = (float*)d_out;

  // ws: [0,16K) flags; ring f16[6][8][B][H] (3 MB); h5buf f32[B][H]
  unsigned* flags = (unsigned*)d_ws;
  unsigned short* ring = (unsigned short*)((char*)d_ws + 16384);
  float* h5buf = (float*)((char*)d_ws + 16384 + (size_t)NL * RD * B * H * 2);

  hipMemsetAsync(d_ws, 0, 16384, stream);   // flags monotonic within a call

  lstm_pipe<<<NBLK_P, 1024, 0, stream>>>(x, Wih0, WihR, Whh, bih, bhh,
                                         ring, h5buf, flags);
  fc_kernel<<<1, 640, 0, stream>>>(h5buf, fcw, fcb, out);
}

// Round 15
// 1245.776 us; speedup vs baseline: 4.5017x; 4.5017x over previous
//
#include <hip/hip_runtime.h>

#define B 64
#define T 256
#define H 512
#define G4 2048
#define D0 128
#define NL 6
#define NBLK_P 192            // 6 layers x 32 col-groups
#define SKEW 2                // layer skew: inter-layer slack = 1 step
#define GTOT (T + SKEW * (NL - 1))   // 266 global steps
#define FSTRIDE 16            // u32 stride between per-block flags (64B)
#define RD 8                  // ring depth (slots/layer); WAR slack = 5
#define HSTRA 584             // h_sA row stride f16 (1168B == 16 mod 128)
#define HSTRB 520             // h_sB row stride f16 (1040B == 16 mod 128)
#define GSTR 36               // g_par row stride f32

typedef float f32x4 __attribute__((ext_vector_type(4)));
typedef float f32x16 __attribute__((ext_vector_type(16)));
typedef _Float16 h16x8 __attribute__((ext_vector_type(8)));

// Coherent 16B load (r9-r12 proven in the STAGED pattern — r14 proved the
// per-wave scattered variant is an HBM storm; staged only).
#define CLOAD(dst, p) \
  asm volatile("global_load_dwordx4 %0, %1, off sc0 sc1" : "=&v"(dst) : "v"(p))
#define VMWAIT do { asm volatile("s_waitcnt vmcnt(0)" ::: "memory"); \
                    __builtin_amdgcn_sched_barrier(0); } while (0)

// ===========================================================================
// lstm_pipe v7 — r12 dataflow (staged LDS, linear ring, sc1 publish) with a
// SPLIT-PHASE skewed schedule. t = g - 2l.
//  Phase A (input half, ready 1 step early due to skew-2):
//    waitA: l-1 flag >= g-1 (slack 1), l+1 flag >= g-5 (WAR, slack 5)
//    stage h_{l-1}(t) -> h_sA, 8 MFMAs (aA frags)
//  Phase B (the tight recurrence edge):
//    waitB: own-layer sibling flags >= g   [the ONLY tight wait]
//    stage h_l(t-1) -> h_sB, 8 MFMAs (aB), g_par reduce, pointwise,
//    publish (r12 verbatim), flag.
//  Critical loop: detect -> stage 64KB -> 8 MFMA -> reduce -> publish.
//  Phase A runs in the sibling-publish propagation shadow (r7 lesson
//  respected: work is REORDERED, not added).
//  g_par (73.7KB) aliases h_sA (74.75KB): last h_sA read (phase-A MFMA)
//  precedes waitB sync; reduce reads precede the publish-drain sync that
//  precedes next step's stageA writes.
//  Deadlock-free: every wait references strictly-earlier progress of other
//  layers (l-1: g-1; l+1: g-5) or completed sibling steps (g); 192 blocks
//  = 1/CU co-resident. WAR bound: l-1 overwriting our rgA slot (its step
//  g+6) requires OUR flag >= g+1 -> blocked until we finish reading (step g).
// ===========================================================================
__global__ void __launch_bounds__(1024, 4) lstm_pipe(
    const float* __restrict__ x,
    const float* __restrict__ Wih0, const float* __restrict__ WihR,
    const float* __restrict__ Whh,
    const float* __restrict__ bih, const float* __restrict__ bhh,
    unsigned short* __restrict__ ring, float* __restrict__ h5,
    unsigned* __restrict__ flags)
{
  __shared__ unsigned short h_sA[64 * HSTRA];   // 74752 B (g_par aliases)
  __shared__ unsigned short h_sB[64 * HSTRB];   // 66560 B
  float* const g_par = (float*)h_sA;

  const int tid  = threadIdx.x;
  const int lane = tid & 63;
  const int wl   = __builtin_amdgcn_readfirstlane(tid >> 6);
  const int ks   = wl & 3;
  const int rt   = (wl >> 2) >> 1;
  const int bt   = (wl >> 2) & 1;
  const int blk  = (int)blockIdx.x;
  const int l    = blk >> 5;
  const int jb   = blk & 31;
  const int j0   = jb * 16;
  const int Kin  = (l == 0) ? D0 : H;
  const int KA4  = Kin >> 2;                // per-ks k width, phase A
  const int FA   = KA4 >> 4;                // phase-A frags: 2 or 8

  const float* WihA = (l == 0) ? Wih0 : (WihR + (size_t)(l - 1) * G4 * H);
  const float* WhhA = Whh + (size_t)l * G4 * H;

  // ---- one-time: W -> A-fragments in registers (f16; r12-verified map) ----
  h16x8 aA[8], aB[8];
  {
    const int ri   = rt * 32 + (lane & 31);
    const int grow = (ri >> 4) * H + j0 + (ri & 15);
    const float* wihRow = WihA + (size_t)grow * Kin;
    const float* whhRow = WhhA + (size_t)grow * H;
    const int klane = (lane >> 5) * 8;
#pragma unroll
    for (int m = 0; m < 8; ++m) {
      h16x8 fa = {};
      if (m < FA) {
        const float* src = wihRow + ks * KA4 + m * 16 + klane;
        f32x4 v0 = *(const f32x4*)src, v1 = *(const f32x4*)(src + 4);
        fa[0] = (_Float16)v0.x; fa[1] = (_Float16)v0.y;
        fa[2] = (_Float16)v0.z; fa[3] = (_Float16)v0.w;
        fa[4] = (_Float16)v1.x; fa[5] = (_Float16)v1.y;
        fa[6] = (_Float16)v1.z; fa[7] = (_Float16)v1.w;
      }
      aA[m] = fa;
      const float* srb = whhRow + ks * 128 + m * 16 + klane;
      f32x4 w0 = *(const f32x4*)srb, w1 = *(const f32x4*)(srb + 4);
      h16x8 fb;
      fb[0] = (_Float16)w0.x; fb[1] = (_Float16)w0.y;
      fb[2] = (_Float16)w0.z; fb[3] = (_Float16)w0.w;
      fb[4] = (_Float16)w1.x; fb[5] = (_Float16)w1.y;
      fb[6] = (_Float16)w1.z; fb[7] = (_Float16)w1.w;
      aB[m] = fb;
    }
  }

  // pointwise ownership + bias (r12 verbatim)
  const int pb = tid >> 4, pcj = tid & 15;
  float bias4[4];
#pragma unroll
  for (int gi = 0; gi < 4; ++gi) {
    int grow = gi * H + j0 + pcj;
    bias4[gi] = bih[(size_t)l * G4 + grow] + bhh[(size_t)l * G4 + grow];
  }

  const int koff = (lane >> 5) * 8;   // B-frag k offset within 16-wide frag
  float creg = 0.f;

  for (int g = 0; g < GTOT; ++g) {
    const int t = g - SKEW * l;
    const bool active = (t >= 0) && (t < T);

    if (active) {
      // ================= PHASE A (slack edges) =================
      if (g > 0) {
        if (tid < 32) {          // l-1 published h_{l-1}(t) at step g-2
          if (l > 0) {
            unsigned* f = &flags[((l - 1) * 32 + tid) * FSTRIDE];
            while ((int)__hip_atomic_load(f, __ATOMIC_RELAXED,
                                          __HIP_MEMORY_SCOPE_AGENT) < g - 1)
              __builtin_amdgcn_s_sleep(1);
          }
        } else if (tid < 64) {   // WAR: l+1 done reading our slot t-8
          if (l < NL - 1) {
            unsigned* f = &flags[((l + 1) * 32 + (tid - 32)) * FSTRIDE];
            while ((int)__hip_atomic_load(f, __ATOMIC_RELAXED,
                                          __HIP_MEMORY_SCOPE_AGENT) < g - 5)
              __builtin_amdgcn_s_sleep(1);
          }
        }
        __syncthreads();
      }

      // stage inA -> h_sA (r12 staged pattern)
      if (l == 0) {
        const int row = tid >> 4, u = tid & 15;
        const float* xr = x + ((size_t)row * T + t) * D0 + u * 8;
        f32x4 v0 = *(const f32x4*)xr, v1 = *(const f32x4*)(xr + 4);
        h16x8 f;
        f[0] = (_Float16)v0.x; f[1] = (_Float16)v0.y;
        f[2] = (_Float16)v0.z; f[3] = (_Float16)v0.w;
        f[4] = (_Float16)v1.x; f[5] = (_Float16)v1.y;
        f[6] = (_Float16)v1.z; f[7] = (_Float16)v1.w;
        *(h16x8*)&h_sA[row * HSTRA + u * 8] = f;
      } else {
        const unsigned short* rgA =
            ring + ((size_t)(l - 1) * RD + (t & (RD - 1))) * (B * H);
        f32x4 rr[4];
#pragma unroll
        for (int i = 0; i < 4; ++i) {
          int uu = tid + 1024 * i;
          CLOAD(rr[i], rgA + (size_t)(uu >> 6) * H + (uu & 63) * 8);
        }
        VMWAIT;
#pragma unroll
        for (int i = 0; i < 4; ++i) {
          int uu = tid + 1024 * i;
          *(f32x4*)&h_sA[(uu >> 6) * HSTRA + (uu & 63) * 8] = rr[i];
        }
      }
      __syncthreads();   // h_sA staged

      f32x16 accv = {};
      {
        const unsigned short* ba =
            &h_sA[(bt * 32 + (lane & 31)) * HSTRA + ks * KA4 + koff];
#pragma unroll
        for (int m = 0; m < 8; ++m) {
          if (m < FA) {
            h16x8 b8 = *(const h16x8*)(ba + m * 16);
            accv = __builtin_amdgcn_mfma_f32_32x32x16_f16(aA[m], b8, accv, 0, 0, 0);
          }
        }
      }

      // ================= PHASE B (tight recurrence edge) =================
      if (t > 0 && tid < 32) {   // siblings published h_l(t-1): flag >= g
        unsigned* f = &flags[(l * 32 + tid) * FSTRIDE];
        while ((int)__hip_atomic_load(f, __ATOMIC_RELAXED,
                                      __HIP_MEMORY_SCOPE_AGENT) < g)
          __builtin_amdgcn_s_sleep(1);
      }
      __syncthreads();           // also orders: phase-A MFMA before g_par

      if (t > 0) {
        const unsigned short* rgB =
            ring + ((size_t)l * RD + ((t - 1) & (RD - 1))) * (B * H);
        f32x4 rr[4];
#pragma unroll
        for (int i = 0; i < 4; ++i) {
          int uu = tid + 1024 * i;
          CLOAD(rr[i], rgB + (size_t)(uu >> 6) * H + (uu & 63) * 8);
        }
        VMWAIT;
#pragma unroll
        for (int i = 0; i < 4; ++i) {
          int uu = tid + 1024 * i;
          *(f32x4*)&h_sB[(uu >> 6) * HSTRB + (uu & 63) * 8] = rr[i];
        }
      }
      __syncthreads();   // h_sB staged

      if (t > 0) {
        const unsigned short* bb =
            &h_sB[(bt * 32 + (lane & 31)) * HSTRB + ks * 128 + koff];
#pragma unroll
        for (int m = 0; m < 8; ++m) {
          h16x8 b8 = *(const h16x8*)(bb + m * 16);
          accv = __builtin_amdgcn_mfma_f32_32x32x16_f16(aB[m], b8, accv, 0, 0, 0);
        }
      }

      // ---- k-slice partials -> g_par (aliases h_sA; r12 verbatim) ----
      {
        float* gp = g_par +
            (size_t)((ks * 4 + (rt * 2 + bt)) * 32 + (lane & 31)) * GSTR +
            4 * (lane >> 5);
#pragma unroll
        for (int q = 0; q < 4; ++q) {
          f32x4 tv;
          tv.x = accv[4 * q];     tv.y = accv[4 * q + 1];
          tv.z = accv[4 * q + 2]; tv.w = accv[4 * q + 3];
          *(f32x4*)&gp[8 * q] = tv;
        }
      }
      __syncthreads();

      // ---- reduce + bias + pointwise + publish (r12 verbatim) ----
      {
        float gt[4];
#pragma unroll
        for (int gi = 0; gi < 4; ++gi) {
          int rowL = gi * 16 + pcj;
          int tile = (rowL >> 5) * 2 + (pb >> 5);
          int rL   = rowL & 31;
          float s = bias4[gi];
#pragma unroll
          for (int ksi = 0; ksi < 4; ++ksi)
            s += g_par[(size_t)((ksi * 4 + tile) * 32 + (pb & 31)) * GSTR + rL];
          gt[gi] = s;
        }
        float iv = 1.f / (1.f + expf(-gt[0]));
        float fv = 1.f / (1.f + expf(-gt[1]));
        float gv = tanhf(gt[2]);
        float ov = 1.f / (1.f + expf(-gt[3]));
        creg = fv * creg + iv * gv;
        float hv = ov * tanhf(creg);
        _Float16 hf = (_Float16)hv;
        __hip_atomic_store(
            &ring[((size_t)l * RD + (t & (RD - 1))) * (B * H) + pb * H + j0 + pcj],
            __builtin_bit_cast(unsigned short, hf),
            __ATOMIC_RELAXED, __HIP_MEMORY_SCOPE_AGENT);
        if (l == NL - 1 && t == T - 1)
          h5[pb * H + j0 + pcj] = hv;
      }
      __syncthreads();   // drain publish stores before flagging
    }

    if (tid == 0)
      __hip_atomic_store(&flags[blk * FSTRIDE], (unsigned)(g + 1),
                         __ATOMIC_RELAXED, __HIP_MEMORY_SCOPE_AGENT);
  }
}

// ===========================================================================
// Final FC on h_5(T-1) (f32 side buffer)
// ===========================================================================
__global__ void __launch_bounds__(640) fc_kernel(
    const float* __restrict__ h5, const float* __restrict__ w,
    const float* __restrict__ bias, float* __restrict__ out)
{
  int tid = threadIdx.x;
  if (tid >= 640) return;
  int b = tid / 10, o = tid - b * 10;
  const float* yr = h5 + (size_t)b * H;
  const float* wr = w + (size_t)o * H;
  float acc = bias[o];
  for (int k = 0; k < H; ++k) acc = fmaf(yr[k], wr[k], acc);
  out[b * 10 + o] = acc;
}

extern "C" void kernel_launch(void* const* d_in, const int* in_sizes, int n_in,
                              void* d_out, int out_size, void* d_ws,
                              size_t ws_size, hipStream_t stream)
{
  const float* x    = (const float*)d_in[0];
  const float* Wih0 = (const float*)d_in[1];
  const float* WihR = (const float*)d_in[2];
  const float* Whh  = (const float*)d_in[3];
  const float* bih  = (const float*)d_in[4];
  const float* bhh  = (const float*)d_in[5];
  const float* fcw  = (const float*)d_in[6];
  const float* fcb  = (const float*)d_in[7];
  float* out = (float*)d_out;

  // ws: [0,16K) flags; ring f16[6][8][B][H] (3 MB); h5buf f32[B][H]
  unsigned* flags = (unsigned*)d_ws;
  unsigned short* ring = (unsigned short*)((char*)d_ws + 16384);
  float* h5buf = (float*)((char*)d_ws + 16384 + (size_t)NL * RD * B * H * 2);

  hipMemsetAsync(d_ws, 0, 16384, stream);   // flags monotonic within a call

  lstm_pipe<<<NBLK_P, 1024, 0, stream>>>(x, Wih0, WihR, Whh, bih, bhh,
                                         ring, h5buf, flags);
  fc_kernel<<<1, 640, 0, stream>>>(h5buf, fcw, fcb, out);
}

// Round 16
// 1181.037 us; speedup vs baseline: 4.7484x; 1.0548x over previous
//
#include <hip/hip_runtime.h>

#define B 64
#define T 256
#define H 512
#define G4 2048
#define D0 128
#define NL 6
#define NBLK_P 192            // 6 layers x 32 col-groups
#define SKEW 2                // layer skew: inter-layer slack = 1 step
#define GTOT (T + SKEW * (NL - 1))   // 266 global steps
#define FSTRIDE 16            // u32 stride between per-block flags (64B)
#define RD 8                  // fallback ring depth
#define HSTRA 584             // h_sA row stride f16 (1168B == 16 mod 128)
#define HSTRB 520             // h_sB row stride f16 (1040B == 16 mod 128)
#define GSTR 36               // g_par row stride f32

typedef float f32x4 __attribute__((ext_vector_type(4)));
typedef float f32x16 __attribute__((ext_vector_type(16)));
typedef _Float16 h16x8 __attribute__((ext_vector_type(8)));

#define CLOAD(dst, p) \
  asm volatile("global_load_dwordx4 %0, %1, off sc0 sc1" : "=&v"(dst) : "v"(p))
#define VMWAIT do { asm volatile("s_waitcnt vmcnt(0)" ::: "memory"); \
                    __builtin_amdgcn_sched_barrier(0); } while (0)

// ===========================================================================
// lstm_pipe v8 — r15 split-phase skewed schedule; ring variant templated.
//  L2C=1 (primary): FULL-DEPTH ring ring[l][t][B][H] f16 (96 MB) — every
//    slot written once per call -> NO address reuse -> consumer reads are
//    plain CACHED loads. First touch on an XCD misses L2 and fills from L3
//    with fresh data (producers write through to the coherence point, and
//    ALL producer flags are polled before any read so lines are fully
//    written). ~24 blocks/XCD then HIT L2 for the same 64KB slab: the
//    all-to-all h broadcast becomes L2-served (r15 paid L3 latency+BW on
//    every read via sc0sc1, since RD=8 slots were re-written every 8 steps).
//    No reuse also deletes the l+1 WAR wait.
//  L2C=0 (fallback, ws too small): r15 verbatim (RD=8 + CLOAD + WAR wait).
//  Everything else r15/r12 proven: phase A (slack edge l-1 >= g-1, stage
//  h_{l-1}(t), 8 MFMA) -> phase B (tight sibling edge >= g, stage h_l(t-1),
//  8 MFMA, g_par reduce, pointwise, sc1 publish, flag).
// ===========================================================================
template<int L2C>
__global__ void __launch_bounds__(1024, 4) lstm_pipe(
    const float* __restrict__ x,
    const float* __restrict__ Wih0, const float* __restrict__ WihR,
    const float* __restrict__ Whh,
    const float* __restrict__ bih, const float* __restrict__ bhh,
    unsigned short* __restrict__ ring, float* __restrict__ h5,
    unsigned* __restrict__ flags)
{
  __shared__ unsigned short h_sA[64 * HSTRA];   // 74752 B (g_par aliases)
  __shared__ unsigned short h_sB[64 * HSTRB];   // 66560 B
  float* const g_par = (float*)h_sA;

  const int tid  = threadIdx.x;
  const int lane = tid & 63;
  const int wl   = __builtin_amdgcn_readfirstlane(tid >> 6);
  const int ks   = wl & 3;
  const int rt   = (wl >> 2) >> 1;
  const int bt   = (wl >> 2) & 1;
  const int blk  = (int)blockIdx.x;
  const int l    = blk >> 5;
  const int jb   = blk & 31;
  const int j0   = jb * 16;
  const int Kin  = (l == 0) ? D0 : H;
  const int KA4  = Kin >> 2;                // per-ks k width, phase A
  const int FA   = KA4 >> 4;                // phase-A frags: 2 or 8

  const float* WihA = (l == 0) ? Wih0 : (WihR + (size_t)(l - 1) * G4 * H);
  const float* WhhA = Whh + (size_t)l * G4 * H;

  // ---- one-time: W -> A-fragments in registers (f16; r12-verified map) ----
  h16x8 aA[8], aB[8];
  {
    const int ri   = rt * 32 + (lane & 31);
    const int grow = (ri >> 4) * H + j0 + (ri & 15);
    const float* wihRow = WihA + (size_t)grow * Kin;
    const float* whhRow = WhhA + (size_t)grow * H;
    const int klane = (lane >> 5) * 8;
#pragma unroll
    for (int m = 0; m < 8; ++m) {
      h16x8 fa = {};
      if (m < FA) {
        const float* src = wihRow + ks * KA4 + m * 16 + klane;
        f32x4 v0 = *(const f32x4*)src, v1 = *(const f32x4*)(src + 4);
        fa[0] = (_Float16)v0.x; fa[1] = (_Float16)v0.y;
        fa[2] = (_Float16)v0.z; fa[3] = (_Float16)v0.w;
        fa[4] = (_Float16)v1.x; fa[5] = (_Float16)v1.y;
        fa[6] = (_Float16)v1.z; fa[7] = (_Float16)v1.w;
      }
      aA[m] = fa;
      const float* srb = whhRow + ks * 128 + m * 16 + klane;
      f32x4 w0 = *(const f32x4*)srb, w1 = *(const f32x4*)(srb + 4);
      h16x8 fb;
      fb[0] = (_Float16)w0.x; fb[1] = (_Float16)w0.y;
      fb[2] = (_Float16)w0.z; fb[3] = (_Float16)w0.w;
      fb[4] = (_Float16)w1.x; fb[5] = (_Float16)w1.y;
      fb[6] = (_Float16)w1.z; fb[7] = (_Float16)w1.w;
      aB[m] = fb;
    }
  }

  const int pb = tid >> 4, pcj = tid & 15;
  float bias4[4];
#pragma unroll
  for (int gi = 0; gi < 4; ++gi) {
    int grow = gi * H + j0 + pcj;
    bias4[gi] = bih[(size_t)l * G4 + grow] + bhh[(size_t)l * G4 + grow];
  }

  const int koff = (lane >> 5) * 8;
  float creg = 0.f;

  for (int g = 0; g < GTOT; ++g) {
    const int t = g - SKEW * l;
    const bool active = (t >= 0) && (t < T);

    if (active) {
      // ================= PHASE A (slack edges) =================
      if (g > 0) {
        if (tid < 32) {          // l-1 published h_{l-1}(t) at step g-2
          if (l > 0) {
            unsigned* f = &flags[((l - 1) * 32 + tid) * FSTRIDE];
            while ((int)__hip_atomic_load(f, __ATOMIC_RELAXED,
                                          __HIP_MEMORY_SCOPE_AGENT) < g - 1)
              __builtin_amdgcn_s_sleep(1);
          }
        } else if (!L2C && tid < 64) {   // WAR (fallback ring only)
          if (l < NL - 1) {
            unsigned* f = &flags[((l + 1) * 32 + (tid - 32)) * FSTRIDE];
            while ((int)__hip_atomic_load(f, __ATOMIC_RELAXED,
                                          __HIP_MEMORY_SCOPE_AGENT) < g - 5)
              __builtin_amdgcn_s_sleep(1);
          }
        }
        __syncthreads();
      }

      // stage inA -> h_sA
      if (l == 0) {
        const int row = tid >> 4, u = tid & 15;
        const float* xr = x + ((size_t)row * T + t) * D0 + u * 8;
        f32x4 v0 = *(const f32x4*)xr, v1 = *(const f32x4*)(xr + 4);
        h16x8 f;
        f[0] = (_Float16)v0.x; f[1] = (_Float16)v0.y;
        f[2] = (_Float16)v0.z; f[3] = (_Float16)v0.w;
        f[4] = (_Float16)v1.x; f[5] = (_Float16)v1.y;
        f[6] = (_Float16)v1.z; f[7] = (_Float16)v1.w;
        *(h16x8*)&h_sA[row * HSTRA + u * 8] = f;
      } else {
        const int slotA = L2C ? t : (t & (RD - 1));
        const unsigned short* rgA =
            ring + ((size_t)(l - 1) * (L2C ? T : RD) + slotA) * (B * H);
        f32x4 rr[4];
        if (L2C) {
#pragma unroll
          for (int i = 0; i < 4; ++i) {
            int uu = tid + 1024 * i;
            rr[i] = *(const f32x4*)(rgA + (size_t)(uu >> 6) * H + (uu & 63) * 8);
          }
        } else {
#pragma unroll
          for (int i = 0; i < 4; ++i) {
            int uu = tid + 1024 * i;
            CLOAD(rr[i], rgA + (size_t)(uu >> 6) * H + (uu & 63) * 8);
          }
          VMWAIT;
        }
#pragma unroll
        for (int i = 0; i < 4; ++i) {
          int uu = tid + 1024 * i;
          *(f32x4*)&h_sA[(uu >> 6) * HSTRA + (uu & 63) * 8] = rr[i];
        }
      }
      __syncthreads();   // h_sA staged

      f32x16 accv = {};
      {
        const unsigned short* ba =
            &h_sA[(bt * 32 + (lane & 31)) * HSTRA + ks * KA4 + koff];
#pragma unroll
        for (int m = 0; m < 8; ++m) {
          if (m < FA) {
            h16x8 b8 = *(const h16x8*)(ba + m * 16);
            accv = __builtin_amdgcn_mfma_f32_32x32x16_f16(aA[m], b8, accv, 0, 0, 0);
          }
        }
      }

      // ================= PHASE B (tight recurrence edge) =================
      if (t > 0 && tid < 32) {   // siblings published h_l(t-1): flag >= g
        unsigned* f = &flags[(l * 32 + tid) * FSTRIDE];
        while ((int)__hip_atomic_load(f, __ATOMIC_RELAXED,
                                      __HIP_MEMORY_SCOPE_AGENT) < g)
          __builtin_amdgcn_s_sleep(1);
      }
      __syncthreads();           // also orders: phase-A MFMA before g_par

      if (t > 0) {
        const int slotB = L2C ? (t - 1) : ((t - 1) & (RD - 1));
        const unsigned short* rgB =
            ring + ((size_t)l * (L2C ? T : RD) + slotB) * (B * H);
        f32x4 rr[4];
        if (L2C) {
#pragma unroll
          for (int i = 0; i < 4; ++i) {
            int uu = tid + 1024 * i;
            rr[i] = *(const f32x4*)(rgB + (size_t)(uu >> 6) * H + (uu & 63) * 8);
          }
        } else {
#pragma unroll
          for (int i = 0; i < 4; ++i) {
            int uu = tid + 1024 * i;
            CLOAD(rr[i], rgB + (size_t)(uu >> 6) * H + (uu & 63) * 8);
          }
          VMWAIT;
        }
#pragma unroll
        for (int i = 0; i < 4; ++i) {
          int uu = tid + 1024 * i;
          *(f32x4*)&h_sB[(uu >> 6) * HSTRB + (uu & 63) * 8] = rr[i];
        }
      }
      __syncthreads();   // h_sB staged

      if (t > 0) {
        const unsigned short* bb =
            &h_sB[(bt * 32 + (lane & 31)) * HSTRB + ks * 128 + koff];
#pragma unroll
        for (int m = 0; m < 8; ++m) {
          h16x8 b8 = *(const h16x8*)(bb + m * 16);
          accv = __builtin_amdgcn_mfma_f32_32x32x16_f16(aB[m], b8, accv, 0, 0, 0);
        }
      }

      // ---- k-slice partials -> g_par (aliases h_sA) ----
      {
        float* gp = g_par +
            (size_t)((ks * 4 + (rt * 2 + bt)) * 32 + (lane & 31)) * GSTR +
            4 * (lane >> 5);
#pragma unroll
        for (int q = 0; q < 4; ++q) {
          f32x4 tv;
          tv.x = accv[4 * q];     tv.y = accv[4 * q + 1];
          tv.z = accv[4 * q + 2]; tv.w = accv[4 * q + 3];
          *(f32x4*)&gp[8 * q] = tv;
        }
      }
      __syncthreads();

      // ---- reduce + bias + pointwise + publish ----
      {
        float gt[4];
#pragma unroll
        for (int gi = 0; gi < 4; ++gi) {
          int rowL = gi * 16 + pcj;
          int tile = (rowL >> 5) * 2 + (pb >> 5);
          int rL   = rowL & 31;
          float s = bias4[gi];
#pragma unroll
          for (int ksi = 0; ksi < 4; ++ksi)
            s += g_par[(size_t)((ksi * 4 + tile) * 32 + (pb & 31)) * GSTR + rL];
          gt[gi] = s;
        }
        float iv = 1.f / (1.f + expf(-gt[0]));
        float fv = 1.f / (1.f + expf(-gt[1]));
        float gv = tanhf(gt[2]);
        float ov = 1.f / (1.f + expf(-gt[3]));
        creg = fv * creg + iv * gv;
        float hv = ov * tanhf(creg);
        _Float16 hf = (_Float16)hv;
        const int slotW = L2C ? t : (t & (RD - 1));
        __hip_atomic_store(
            &ring[((size_t)l * (L2C ? T : RD) + slotW) * (B * H) + pb * H + j0 + pcj],
            __builtin_bit_cast(unsigned short, hf),
            __ATOMIC_RELAXED, __HIP_MEMORY_SCOPE_AGENT);
        if (l == NL - 1 && t == T - 1)
          h5[pb * H + j0 + pcj] = hv;
      }
      __syncthreads();   // drain publish stores before flagging
    }

    if (tid == 0)
      __hip_atomic_store(&flags[blk * FSTRIDE], (unsigned)(g + 1),
                         __ATOMIC_RELAXED, __HIP_MEMORY_SCOPE_AGENT);
  }
}

// ===========================================================================
// Final FC on h_5(T-1) (f32 side buffer)
// ===========================================================================
__global__ void __launch_bounds__(640) fc_kernel(
    const float* __restrict__ h5, const float* __restrict__ w,
    const float* __restrict__ bias, float* __restrict__ out)
{
  int tid = threadIdx.x;
  if (tid >= 640) return;
  int b = tid / 10, o = tid - b * 10;
  const float* yr = h5 + (size_t)b * H;
  const float* wr = w + (size_t)o * H;
  float acc = bias[o];
  for (int k = 0; k < H; ++k) acc = fmaf(yr[k], wr[k], acc);
  out[b * 10 + o] = acc;
}

extern "C" void kernel_launch(void* const* d_in, const int* in_sizes, int n_in,
                              void* d_out, int out_size, void* d_ws,
                              size_t ws_size, hipStream_t stream)
{
  const float* x    = (const float*)d_in[0];
  const float* Wih0 = (const float*)d_in[1];
  const float* WihR = (const float*)d_in[2];
  const float* Whh  = (const float*)d_in[3];
  const float* bih  = (const float*)d_in[4];
  const float* bhh  = (const float*)d_in[5];
  const float* fcw  = (const float*)d_in[6];
  const float* fcb  = (const float*)d_in[7];
  float* out = (float*)d_out;

  unsigned* flags = (unsigned*)d_ws;
  unsigned short* ring = (unsigned short*)((char*)d_ws + 16384);

  const size_t ringFull = (size_t)NL * T * B * H * 2;      // 96 MB
  const size_t ringFall = (size_t)NL * RD * B * H * 2;     // 3 MB
  const size_t needFull = 16384 + ringFull + (size_t)B * H * 4;

  hipMemsetAsync(d_ws, 0, 16384, stream);   // flags monotonic within a call

  if (ws_size >= needFull) {
    float* h5buf = (float*)((char*)d_ws + 16384 + ringFull);
    lstm_pipe<1><<<NBLK_P, 1024, 0, stream>>>(x, Wih0, WihR, Whh, bih, bhh,
                                              ring, h5buf, flags);
    fc_kernel<<<1, 640, 0, stream>>>(h5buf, fcw, fcb, out);
  } else {
    float* h5buf = (float*)((char*)d_ws + 16384 + ringFall);
    lstm_pipe<0><<<NBLK_P, 1024, 0, stream>>>(x, Wih0, WihR, Whh, bih, bhh,
                                              ring, h5buf, flags);
    fc_kernel<<<1, 640, 0, stream>>>(h5buf, fcw, fcb, out);
  }
}